// Round 2
// 231.247 us; speedup vs baseline: 1.0296x; 1.0296x over previous
//
#include <hip/hip_runtime.h>

// Problem constants (static per reference setup_inputs)
#define NSEQ   8
#define QLEN   128
#define NQH    32
#define NKVH   8
#define GQ     4        // NQH / NKVH
#define HD     128
#define BLK    16
#define MAXBLK 128
#define LTOT   2048     // MAXBLK * BLK
#define NSEGC  4
#define TILEC  32

typedef __attribute__((ext_vector_type(8)))  short  shortx8;
typedef __attribute__((ext_vector_type(16))) float  floatx16;
typedef __attribute__((ext_vector_type(4)))  float  fx4;
typedef __attribute__((ext_vector_type(4)))  int    intx4;
typedef __attribute__((ext_vector_type(2)))  __bf16 bf16x2;

// Native RNE f32->bf16 (compiler emits v_cvt_pk_bf16_f32 for pairs; same
// rounding as the previous integer RNE -> bit-identical results).
__device__ __forceinline__ short f2bf(float f) {
    return __builtin_bit_cast(short, (__bf16)f);
}
__device__ __forceinline__ int pk2(float a, float b) {
    bf16x2 t; t[0] = (__bf16)a; t[1] = (__bf16)b;
    return __builtin_bit_cast(int, t);
}

// One workgroup = (seq s, kv-head h, segment seg, q-half qh).
// 512 threads = 8 waves; wave w owns 32 q-rows. Segment = up to 512 keys,
// 8 tiles of 64 keys. S^T = K @ Q^T via mfma_32x32x16_bf16 (rows=keys,
// cols=q); unshifted p = exp2(z) accumulated into PV; epilogue scales by
// exp2(-max z). P goes C-layout -> A-layout fully in-register via
// v_permlane32_swap_b32 (T12) -- no pbuf LDS round-trip.
__global__ __launch_bounds__(512, 2) void psa_kernel(
    const float* __restrict__ query,
    const float* __restrict__ key_cache,
    const float* __restrict__ value_cache,
    const int*   __restrict__ block_tables,
    const int*   __restrict__ seq_lens,
    const float* __restrict__ scale_p,
    const float* __restrict__ softcap_p,
    float* __restrict__ out)
{
    // All LDS layouts are "contiguous 512B/1KB per wave access" -> conflict-free.
    __shared__ __align__(16) short kbuf[2][16][64][8]; // [dbl][d-chunk][key][8 d]   32 KB
    __shared__ __align__(16) short vbuf[2][8][128][8]; // [dbl][l-slab][d][8 l]      32 KB

    const int bi   = blockIdx.x;
    // XCD-pair swizzle: qh partners (same s,h,seg) share blockIdx%8 -> same XCD L2
    const int p_lo = bi & 7;
    const int qh   = (bi >> 3) & 1;
    const int pp   = (bi >> 4) * 8 + p_lo;
    const int seg  = pp & 3;
    const int h    = (pp >> 2) & 7;
    const int s    = pp >> 5;

    const int tid  = threadIdx.x;
    const int w    = tid >> 6;
    const int lane = tid & 63;
    const int lo   = lane & 31;
    const int hi   = lane >> 5;

    const float NEG_INF = -__builtin_inff();
    const float scale   = *scale_p;
    const float softcap = *softcap_p;
    const int   seq     = seq_lens[s];
    const int   ctx     = seq - QLEN;
    const int   span    = ((seq + NSEGC * TILEC - 1) / (NSEGC * TILEC)) * TILEC;
    const int   seg_start = seg * span;
    int seg_len = LTOT - seg_start;
    if (seg_len > span) seg_len = span;
    const int NT = (seg_len > 0) ? ((seg_len + 63) >> 6) : 0;

    const float LOG2E = 1.4426950408889634f;
    const bool  do_cap = (softcap > 0.0f);
    const float c1 = do_cap ? (2.0f * LOG2E / softcap) : 0.0f;
    const float c2 = do_cap ? (softcap * LOG2E) : 0.0f;

    // ---- persistent Q fragments (B operand: n = q-row = lo, k = d) ----
    const int r_base = qh * 256 + w * 32;
    const int qb     = r_base & 127;       // q_local base (wave-uniform)
    const int g      = r_base >> 7;        // GQA group (wave-uniform)
    const int qrow   = qb + lo;
    const int q_off  = ((s * QLEN + qrow) * NQH + h * GQ + g) * HD;
    shortx8 qfrag[8];
#pragma unroll
    for (int ks = 0; ks < 8; ++ks) {
        const float* qp = query + q_off + ks * 16 + hi * 8;
        fx4 a = *(const fx4*)qp;
        fx4 b = *(const fx4*)(qp + 4);
        intx4 w4 = { pk2(a[0] * scale, a[1] * scale), pk2(a[2] * scale, a[3] * scale),
                     pk2(b[0] * scale, b[1] * scale), pk2(b[2] * scale, b[3] * scale) };
        qfrag[ks] = __builtin_bit_cast(shortx8, w4);
    }

    const int bt_base = s * MAXBLK;

    // staging registers (held across compute so loads overlap it)
    float kreg[2][8];
    fx4   vreg[2][2];
    const int kb  = tid & 63;   // key index for K staging
    const int kdc = tid >> 6;   // d-chunk base for K staging
    const int vd  = tid & 127;  // d for V staging
    const int vlh = tid >> 7;   // l-slab base for V staging

    auto stage_load = [&](int nt) {
        { // K: 8 scalar dwords (stride 64B), coalesced across the 64 b-lanes
            int l_glob = seg_start + nt * 64 + kb;
            if (l_glob >= LTOT) l_glob = LTOT - 1;
            const int pb = block_tables[bt_base + (l_glob >> 4)];
            const float* kp = key_cache + (pb * NKVH + h) * (HD * BLK) + (l_glob & 15);
#pragma unroll
            for (int ic = 0; ic < 2; ++ic)
#pragma unroll
                for (int j = 0; j < 8; ++j)
                    kreg[ic][j] = kp[((kdc + ic * 8) * 8 + j) * BLK];
        }
        { // V: native [d][b] layout is already l-contiguous -> 2x dwordx4
#pragma unroll
            for (int ic = 0; ic < 2; ++ic) {
                const int lslab = vlh + ic * 4;
                int l_glob = seg_start + nt * 64 + lslab * 8;
                if (l_glob >= LTOT) l_glob = LTOT - 8;
                const int pb = block_tables[bt_base + (l_glob >> 4)];
                const float* vp = value_cache + ((pb * NKVH + h) * HD + vd) * BLK + (l_glob & 15);
                vreg[ic][0] = *(const fx4*)vp;
                vreg[ic][1] = *(const fx4*)(vp + 4);
            }
        }
    };
    auto stage_write = [&](int bb_) {
#pragma unroll
        for (int ic = 0; ic < 2; ++ic) {
            intx4 w4 = { pk2(kreg[ic][0], kreg[ic][1]), pk2(kreg[ic][2], kreg[ic][3]),
                         pk2(kreg[ic][4], kreg[ic][5]), pk2(kreg[ic][6], kreg[ic][7]) };
            *(intx4*)(&kbuf[bb_][kdc + ic * 8][kb][0]) = w4;   // ds_write_b128
        }
#pragma unroll
        for (int ic = 0; ic < 2; ++ic) {
            intx4 w4 = { pk2(vreg[ic][0][0], vreg[ic][0][1]), pk2(vreg[ic][0][2], vreg[ic][0][3]),
                         pk2(vreg[ic][1][0], vreg[ic][1][1]), pk2(vreg[ic][1][2], vreg[ic][1][3]) };
            *(intx4*)(&vbuf[bb_][vlh + ic * 4][vd][0]) = w4;   // ds_write_b128
        }
    };

    floatx16 acc[4];
#pragma unroll
    for (int dt = 0; dt < 4; ++dt)
#pragma unroll
        for (int i = 0; i < 16; ++i) acc[dt][i] = 0.0f;
    float m_run = NEG_INF;

    if (NT > 0) { stage_load(0); stage_write(0); }

    for (int nt = 0; nt < NT; ++nt) {
        const int bb = nt & 1;
        __syncthreads();
        const bool pre = (nt + 1 < NT);
        if (pre) stage_load(nt + 1);   // global->VGPR; overlaps compute below

        const int tile_l0 = seg_start + nt * 64;
        const bool need_mask = (tile_l0 + 63 > ctx + qb) || (nt * 64 + 63 >= seg_len);

#pragma unroll
        for (int nsub = 0; nsub < 2; ++nsub) {
            // S^T tile: A = K (m=key), B = Q^T (n=q)
            floatx16 c;
#pragma unroll
            for (int i = 0; i < 16; ++i) c[i] = 0.0f;
#pragma unroll
            for (int ks = 0; ks < 8; ++ks) {
                shortx8 af = *(const shortx8*)(&kbuf[bb][ks * 2 + hi][nsub * 32 + lo][0]);
                c = __builtin_amdgcn_mfma_f32_32x32x16_bf16(af, qfrag[ks], c, 0, 0, 0);
            }
            // softcap in log2 space: z = log2e * softcap * tanh(s/softcap)
            float z[16];
            float mloc = NEG_INF;
#pragma unroll
            for (int r = 0; r < 16; ++r) {
                const float si = c[r];
                float zz;
                if (do_cap) {
                    const float u  = __builtin_amdgcn_exp2f(si * c1);
                    const float rr = __builtin_amdgcn_rcpf(u + 1.0f);
                    zz = c2 - (2.0f * c2) * rr;
                } else {
                    zz = si * LOG2E;
                }
                if (need_mask) {
                    const int key   = nsub * 32 + (r & 3) + 8 * (r >> 2) + 4 * hi;
                    const int l_loc = nt * 64 + key;
                    const bool ok = (l_loc < seg_len) && (tile_l0 + key <= ctx + qb + lo);
                    zz = ok ? zz : NEG_INF;
                }
                z[r] = zz;
                mloc = fmaxf(mloc, zz);
            }
            mloc  = fmaxf(mloc, __shfl_xor(mloc, 32, 64)); // lane now has max for q=lo
            m_run = fmaxf(m_run, mloc);

            // p = exp2(z) (unshifted), packed to bf16 pairs; C-layout -> A-layout
            // via v_permlane32_swap_b32: lane(lo,0) holds keys {0..3,8..11,...},
            // lane(lo,1) holds {4..7,12..15,...}; swapping Ai's upper half with
            // A(i+2)'s lower half yields both A-fragment dwords per swap.
            int A[8];
#pragma unroll
            for (int i = 0; i < 8; ++i)
                A[i] = pk2(__builtin_amdgcn_exp2f(z[2 * i]),
                           __builtin_amdgcn_exp2f(z[2 * i + 1]));
            auto s0 = __builtin_amdgcn_permlane32_swap(A[0], A[2], false, false);
            auto s1 = __builtin_amdgcn_permlane32_swap(A[1], A[3], false, false);
            auto s2 = __builtin_amdgcn_permlane32_swap(A[4], A[6], false, false);
            auto s3 = __builtin_amdgcn_permlane32_swap(A[5], A[7], false, false);
            intx4 w0 = { (int)s0[0], (int)s1[0], (int)s0[1], (int)s1[1] };
            intx4 w1 = { (int)s2[0], (int)s3[0], (int)s2[1], (int)s3[1] };
            shortx8 pf[2] = { __builtin_bit_cast(shortx8, w0),
                              __builtin_bit_cast(shortx8, w1) };

            // PV for this nsub's 32 keys: A = P (m=q), B = V (n=d); K=16/step
#pragma unroll
            for (int ks2 = 0; ks2 < 2; ++ks2) {
                const int slab = (nsub * 2 + ks2) * 2 + hi;
#pragma unroll
                for (int dt = 0; dt < 4; ++dt) {
                    shortx8 vf = *(const shortx8*)(&vbuf[bb][slab][dt * 32 + lo][0]);
                    acc[dt] = __builtin_amdgcn_mfma_f32_32x32x16_bf16(pf[ks2], vf, acc[dt], 0, 0, 0);
                }
            }
        }

        if (pre) stage_write(bb ^ 1);  // cvt + LDS writes after compute (hides latency)
    }

    // Epilogue: scale by exp2(-max z); broadcast per-row via shfl (q = src lane & 31)
    const float scv = (m_run == NEG_INF) ? 0.0f : __builtin_amdgcn_exp2f(-m_run);
    const int out_base = ((s * QLEN + qb) * NQH + (h * GQ + g)) * (NSEGC * HD) + seg * HD + lo;
#pragma unroll
    for (int r = 0; r < 16; ++r) {
        const int row = (r & 3) + 8 * (r >> 2) + 4 * hi;
        const float sc = __shfl(scv, row, 64);
        const int ob = out_base + row * (NQH * NSEGC * HD);
#pragma unroll
        for (int dt = 0; dt < 4; ++dt)
            out[ob + dt * 32] = acc[dt][r] * sc;
    }
}

extern "C" void kernel_launch(void* const* d_in, const int* in_sizes, int n_in,
                              void* d_out, int out_size, void* d_ws, size_t ws_size,
                              hipStream_t stream) {
    const float* query        = (const float*)d_in[0];
    const float* key_cache    = (const float*)d_in[1];
    const float* value_cache  = (const float*)d_in[2];
    const int*   block_tables = (const int*)d_in[3];
    const int*   seq_lens     = (const int*)d_in[4];
    // d_in[5] query_start_len: implied by uniform QLEN (unused)
    const float* scale_p      = (const float*)d_in[6];
    // d_in[7] k_scale, d_in[8] v_scale: no-ops for fp32 cache path
    const float* softcap_p    = (const float*)d_in[9];

    psa_kernel<<<dim3(512), dim3(512), 0, stream>>>(
        query, key_cache, value_cache, block_tables, seq_lens,
        scale_p, softcap_p, (float*)d_out);
}